// Round 6
// baseline (299.465 us; speedup 1.0000x reference)
//
#include <hip/hip_runtime.h>
#include <hip/hip_bf16.h>

// GAT layer: B=32, N=1024, IN_F=OUT_F=256, alpha=0.2
//  k0: adj (134 MB int32) -> u64 bitmask per 64-j chunk (ballot), 4 MB
//  k1: Wh = bf16(h@W^T) stored in MFMA B-FRAGMENT layout whF (pre-swizzled so
//      k3's loads are lane-contiguous 1KB); fused si/sj. Core = R2-verified.
//  k3: BARRIER-FREE, LDS-FREE fused attention. Each wave autonomous:
//      16 i-rows x 256 o; S computed per-lane directly in A-fragment layout
//      (A[m=ln][k=quad*8+j], m89-verified); Wh B-frags = coalesced whF loads;
//      denominators via wave shuffles only.

#define ALPHA 0.2f

typedef __bf16 bf16x8 __attribute__((ext_vector_type(8)));
typedef __bf16 bf16x4 __attribute__((ext_vector_type(4)));
typedef float  f32x4  __attribute__((ext_vector_type(4)));
typedef unsigned long long u64;

// ---------------- k0: adj -> bitmask ----------------
__global__ __launch_bounds__(256) void k0_mask(const int* __restrict__ adj,
                                               u64* __restrict__ mask) {
    const int wid = (blockIdx.x * 256 + threadIdx.x) >> 6;  // 0..8191
    const int l   = threadIdx.x & 63;
    const size_t base = (size_t)wid * 64;
    #pragma unroll 4
    for (int it = 0; it < 64; ++it) {
        const size_t word = base + it;
        const int v = adj[word * 64 + l];
        const u64 m = __ballot(v > 0);
        if (l == 0) mask[word] = m;
    }
}

// ---------------- k1: Wh = h @ W^T -> whF (fragment layout) + si/sj ----------
// grid 512 x 256 thr; block = 64 n-rows (one j-chunk jc = bx&15) x 256 o.
// whF element layout: frag f = (b*16+jc)*32 + oi*2 + kk holds, at lane l
// (ln=l&15, quad=l>>4), elems Wh[j = jc*64+kk*32+quad*8 .. +7][o = oi*16+ln]
// == B-fragment for mfma(af, bfr) per m89. Stored as whF[f*512 + l*8 .. +7].
__global__ __launch_bounds__(256) void k1_gemm1(const float* __restrict__ h,
                                                const float* __restrict__ W,
                                                const float* __restrict__ a_g,
                                                __bf16* __restrict__ whF,
                                                float* __restrict__ si,
                                                float* __restrict__ sj) {
    __shared__ __bf16 hA[64 * 72];
    __shared__ __bf16 hB[256 * 72];   // W tiles; reused as [o][n] out-staging
    __shared__ float  red[512];
    const int t    = threadIdx.x;
    const int r0   = blockIdx.x * 64;
    const int b    = r0 >> 10;
    const int n0   = r0 & 1023;
    const int jc   = blockIdx.x & 15;
    const int w    = t >> 6;
    const int l    = t & 63;
    const int ln   = l & 15;
    const int quad = l >> 4;

    f32x4 acc[4][4] = {};
    float4 ha_r[4], wb_r[16];

    #pragma unroll
    for (int it = 0; it < 4; ++it)
        ha_r[it] = *(const float4*)&h[(size_t)(r0 + it * 16 + (t >> 4)) * 256 + (t & 15) * 4];
    #pragma unroll
    for (int it = 0; it < 16; ++it)
        wb_r[it] = *(const float4*)&W[(size_t)(it * 16 + (t >> 4)) * 256 + (t & 15) * 4];

    for (int kc = 0; kc < 4; ++kc) {
        #pragma unroll
        for (int it = 0; it < 4; ++it) {
            const float4 v = ha_r[it];
            bf16x4 pv = {(__bf16)v.x, (__bf16)v.y, (__bf16)v.z, (__bf16)v.w};
            *(bf16x4*)&hA[(it * 16 + (t >> 4)) * 72 + (t & 15) * 4] = pv;
        }
        #pragma unroll
        for (int it = 0; it < 16; ++it) {
            const float4 v = wb_r[it];
            bf16x4 pv = {(__bf16)v.x, (__bf16)v.y, (__bf16)v.z, (__bf16)v.w};
            *(bf16x4*)&hB[(it * 16 + (t >> 4)) * 72 + (t & 15) * 4] = pv;
        }
        __syncthreads();
        if (kc < 3) {
            const int k0 = (kc + 1) * 64;
            #pragma unroll
            for (int it = 0; it < 4; ++it)
                ha_r[it] = *(const float4*)&h[(size_t)(r0 + it * 16 + (t >> 4)) * 256 + k0 + (t & 15) * 4];
            #pragma unroll
            for (int it = 0; it < 16; ++it)
                wb_r[it] = *(const float4*)&W[(size_t)(it * 16 + (t >> 4)) * 256 + k0 + (t & 15) * 4];
        }
        #pragma unroll
        for (int kk = 0; kk < 2; ++kk) {
            bf16x8 af[4], bfr[4];
            #pragma unroll
            for (int ri = 0; ri < 4; ++ri)
                af[ri] = *(const bf16x8*)&hA[(ri * 16 + ln) * 72 + kk * 32 + quad * 8];
            #pragma unroll
            for (int oi = 0; oi < 4; ++oi)
                bfr[oi] = *(const bf16x8*)&hB[(w * 64 + oi * 16 + ln) * 72 + kk * 32 + quad * 8];
            #pragma unroll
            for (int ri = 0; ri < 4; ++ri)
                #pragma unroll
                for (int oi = 0; oi < 4; ++oi)
                    acc[ri][oi] = __builtin_amdgcn_mfma_f32_16x16x32_bf16(
                        af[ri], bfr[oi], acc[ri][oi], 0, 0, 0);
        }
        __syncthreads();
    }

    // stage acc -> hB as [o][n_local]  (n_local == j within chunk jc)
    #pragma unroll
    for (int ri = 0; ri < 4; ++ri) {
        const int n = ri * 16 + quad * 4;
        #pragma unroll
        for (int oi = 0; oi < 4; ++oi) {
            const int o = w * 64 + oi * 16 + ln;
            bf16x4 pv = {(__bf16)acc[ri][oi][0], (__bf16)acc[ri][oi][1],
                         (__bf16)acc[ri][oi][2], (__bf16)acc[ri][oi][3]};
            *(bf16x4*)&hB[o * 72 + n] = pv;
        }
    }
    __syncthreads();

    // fragment-layout stores: wave w handles oi = w*4..w*4+3, kk = 0,1.
    // LDS read pattern identical to R2-verified k3 lds_w reads.
    #pragma unroll
    for (int fi = 0; fi < 8; ++fi) {
        const int oi = w * 4 + (fi >> 1);
        const int kk = fi & 1;
        const bf16x8 v = *(const bf16x8*)&hB[(oi * 16 + ln) * 72 + kk * 32 + quad * 8];
        *(bf16x8*)&whF[(size_t)(((b * 16 + jc) * 32) + oi * 2 + kk) * 512 + l * 8] = v;
    }

    // fused si/sj
    {
        float s1 = 0.f, s2 = 0.f;
        #pragma unroll 8
        for (int oi = 0; oi < 64; ++oi) {
            const int o = w * 64 + oi;
            const float v = (float)hB[o * 72 + l];
            s1 += v * a_g[o];
            s2 += v * a_g[256 + o];
        }
        red[w * 64 + l]       = s1;
        red[256 + w * 64 + l] = s2;
    }
    __syncthreads();
    if (t < 64) {
        si[b * 1024 + n0 + t] = red[t] + red[64 + t] + red[128 + t] + red[192 + t];
    } else if (t < 128) {
        const int n = t - 64;
        sj[b * 1024 + n0 + n] = red[256 + n] + red[320 + n] + red[384 + n] + red[448 + n];
    }
}

// ---------------- k3: barrier-free fused attention ----------------
// grid (4, 32) x 1024 thr? No: grid (16, 32), 256 thr, 4 waves; wave w owns
// i-rows [i0 + w*16, +16) x all 256 o. No LDS, no __syncthreads.
__global__ __launch_bounds__(256) void k3_attn(const u64* __restrict__ mask,
                                               const __bf16* __restrict__ whF,
                                               const float* __restrict__ si_g,
                                               const float* __restrict__ sj_g,
                                               float* __restrict__ out) {
    const int t    = threadIdx.x;
    const int b    = blockIdx.y;
    const int i0   = blockIdx.x * 64;
    const int w    = t >> 6;
    const int l    = t & 63;
    const int ln   = l & 15;
    const int quad = l >> 4;

    const int irow = i0 + w * 16 + ln;              // A-frag row this lane supplies
    const float si_r = si_g[b * 1024 + irow];
    const u64* mrow  = mask + (size_t)(b * 1024 + irow) * 16;
    const __bf16* whFb = whF + (size_t)b * 16 * 16384;   // 16 chunks x 32 frags x 512
    const float* sjb = sj_g + b * 1024;

    f32x4 acc[16] = {};
    float dsum = 0.f;

    for (int jc = 0; jc < 16; ++jc) {
        const u64 m64 = mrow[jc];
        #pragma unroll
        for (int kk = 0; kk < 2; ++kk) {
            // issue all 16 B-frag loads (lane-contiguous 1KB each)
            bf16x8 barr[16];
            const __bf16* fp = whFb + (size_t)(jc * 32 + kk) * 512 + l * 8;
            #pragma unroll
            for (int oi = 0; oi < 16; ++oi)
                barr[oi] = *(const bf16x8*)(fp + (size_t)oi * 1024);
            // compute A-frag in registers: S[irow][j], j = jc*64+kk*32+quad*8 ..+7
            const unsigned bits = (unsigned)(m64 >> (kk * 32 + quad * 8)) & 0xFFu;
            const float4 s0 = *(const float4*)&sjb[jc * 64 + kk * 32 + quad * 8];
            const float4 s1 = *(const float4*)&sjb[jc * 64 + kk * 32 + quad * 8 + 4];
            float e0 = si_r + s0.x; e0 = e0 > 0.f ? e0 : ALPHA * e0;
            float e1 = si_r + s0.y; e1 = e1 > 0.f ? e1 : ALPHA * e1;
            float e2 = si_r + s0.z; e2 = e2 > 0.f ? e2 : ALPHA * e2;
            float e3 = si_r + s0.w; e3 = e3 > 0.f ? e3 : ALPHA * e3;
            float e4 = si_r + s1.x; e4 = e4 > 0.f ? e4 : ALPHA * e4;
            float e5 = si_r + s1.y; e5 = e5 > 0.f ? e5 : ALPHA * e5;
            float e6 = si_r + s1.z; e6 = e6 > 0.f ? e6 : ALPHA * e6;
            float e7 = si_r + s1.w; e7 = e7 > 0.f ? e7 : ALPHA * e7;
            bf16x8 af;
            af[0] = (__bf16)((bits &   1u) ? __expf(e0) : 0.f);
            af[1] = (__bf16)((bits &   2u) ? __expf(e1) : 0.f);
            af[2] = (__bf16)((bits &   4u) ? __expf(e2) : 0.f);
            af[3] = (__bf16)((bits &   8u) ? __expf(e3) : 0.f);
            af[4] = (__bf16)((bits &  16u) ? __expf(e4) : 0.f);
            af[5] = (__bf16)((bits &  32u) ? __expf(e5) : 0.f);
            af[6] = (__bf16)((bits &  64u) ? __expf(e6) : 0.f);
            af[7] = (__bf16)((bits & 128u) ? __expf(e7) : 0.f);
            dsum += (float)af[0] + (float)af[1] + (float)af[2] + (float)af[3]
                  + (float)af[4] + (float)af[5] + (float)af[6] + (float)af[7];
            #pragma unroll
            for (int oi = 0; oi < 16; ++oi)
                acc[oi] = __builtin_amdgcn_mfma_f32_16x16x32_bf16(af, barr[oi], acc[oi], 0, 0, 0);
        }
    }

    // row-denominator: sum this lane's partial across the 4 quad-copies of ln
    float tot = dsum;
    tot += __shfl_xor(tot, 16);
    tot += __shfl_xor(tot, 32);      // every lane: total for row (i0+w*16+ln)

    // epilogue: D rows = quad*4+q, cols = oi*16+ln
    #pragma unroll
    for (int q = 0; q < 4; ++q) {
        const float d = __shfl(tot, quad * 4 + q);     // row total for quad*4+q
        const float dinv = 1.0f / fmaxf(d, 1e-30f);
        const size_t rbase = (size_t)(b * 1024 + i0 + w * 16 + quad * 4 + q) * 256;
        #pragma unroll
        for (int oi = 0; oi < 16; ++oi) {
            const float v = acc[oi][q] * dinv;
            out[rbase + oi * 16 + ln] = v > 0.f ? v : __expf(v) - 1.f;
        }
    }
}

extern "C" void kernel_launch(void* const* d_in, const int* in_sizes, int n_in,
                              void* d_out, int out_size, void* d_ws, size_t ws_size,
                              hipStream_t stream) {
    const float* h   = (const float*)d_in[0];
    const int*   adj = (const int*)d_in[1];
    const float* W   = (const float*)d_in[2];
    const float* a   = (const float*)d_in[3];
    float* out = (float*)d_out;

    __bf16* whF  = (__bf16*)d_ws;                                   // 16 MiB
    float*  si   = (float*)((char*)d_ws + (size_t)16777216);        // 128 KiB
    float*  sj   = (float*)((char*)d_ws + (size_t)16777216 + 131072);
    u64*    mask = (u64*)((char*)d_ws + (size_t)16777216 + 262144); // 4 MiB

    k0_mask<<<2048, 256, 0, stream>>>(adj, mask);
    k1_gemm1<<<512, 256, 0, stream>>>(h, W, a, whF, si, sj);
    k3_attn<<<dim3(16, 32), 256, 0, stream>>>(mask, whF, si, sj, out);
}

// Round 7
// 287.815 us; speedup vs baseline: 1.0405x; 1.0405x over previous
//
#include <hip/hip_runtime.h>
#include <hip/hip_bf16.h>

// GAT layer: B=32, N=1024, IN_F=OUT_F=256, alpha=0.2
//  k0: adj (134 MB int32) -> u64 bitmask per 64-j chunk (ballot), 4 MB
//  k1: WhT[b][o][n] = bf16(h@W^T), MFMA; LDS-staged coalesced writes; fused
//      si/sj  (exact R2 code — verified at absmax 1.953e-3)
//  k3: R2 structure; R7 change = XCD-aware 1D block remap so each XCD's
//      resident blocks share 4 batches (2 MB whT working set, fits 4 MB L2)
//      instead of all 32 (16 MB -> thrash). Pure index permutation,
//      bit-identical numerics.

#define ALPHA 0.2f

typedef __bf16 bf16x8 __attribute__((ext_vector_type(8)));
typedef __bf16 bf16x4 __attribute__((ext_vector_type(4)));
typedef float  f32x4  __attribute__((ext_vector_type(4)));
typedef unsigned long long u64;

// ---------------- k0: adj -> bitmask ----------------
__global__ __launch_bounds__(256) void k0_mask(const int* __restrict__ adj,
                                               u64* __restrict__ mask) {
    const int wid = (blockIdx.x * 256 + threadIdx.x) >> 6;  // 0..8191
    const int l   = threadIdx.x & 63;
    const size_t base = (size_t)wid * 64;
    #pragma unroll 4
    for (int it = 0; it < 64; ++it) {
        const size_t word = base + it;
        const int v = adj[word * 64 + l];
        const u64 m = __ballot(v > 0);
        if (l == 0) mask[word] = m;
    }
}

// ---------------- k1: Wh = h @ W^T -> whT (bf16) + si/sj (exact R2) ----------
__global__ __launch_bounds__(256) void k1_gemm1(const float* __restrict__ h,
                                                const float* __restrict__ W,
                                                const float* __restrict__ a_g,
                                                __bf16* __restrict__ whT,
                                                float* __restrict__ si,
                                                float* __restrict__ sj) {
    __shared__ __bf16 hA[64 * 72];
    __shared__ __bf16 hB[256 * 72];   // W tiles; reused as [o][n] out-staging
    __shared__ float  red[512];
    const int t    = threadIdx.x;
    const int r0   = blockIdx.x * 64;
    const int b    = r0 >> 10;
    const int n0   = r0 & 1023;
    const int w    = t >> 6;
    const int l    = t & 63;
    const int ln   = l & 15;
    const int quad = l >> 4;

    f32x4 acc[4][4] = {};
    float4 ha_r[4], wb_r[16];

    #pragma unroll
    for (int it = 0; it < 4; ++it)
        ha_r[it] = *(const float4*)&h[(size_t)(r0 + it * 16 + (t >> 4)) * 256 + (t & 15) * 4];
    #pragma unroll
    for (int it = 0; it < 16; ++it)
        wb_r[it] = *(const float4*)&W[(size_t)(it * 16 + (t >> 4)) * 256 + (t & 15) * 4];

    for (int kc = 0; kc < 4; ++kc) {
        #pragma unroll
        for (int it = 0; it < 4; ++it) {
            const float4 v = ha_r[it];
            bf16x4 pv = {(__bf16)v.x, (__bf16)v.y, (__bf16)v.z, (__bf16)v.w};
            *(bf16x4*)&hA[(it * 16 + (t >> 4)) * 72 + (t & 15) * 4] = pv;
        }
        #pragma unroll
        for (int it = 0; it < 16; ++it) {
            const float4 v = wb_r[it];
            bf16x4 pv = {(__bf16)v.x, (__bf16)v.y, (__bf16)v.z, (__bf16)v.w};
            *(bf16x4*)&hB[(it * 16 + (t >> 4)) * 72 + (t & 15) * 4] = pv;
        }
        __syncthreads();
        if (kc < 3) {
            const int k0 = (kc + 1) * 64;
            #pragma unroll
            for (int it = 0; it < 4; ++it)
                ha_r[it] = *(const float4*)&h[(size_t)(r0 + it * 16 + (t >> 4)) * 256 + k0 + (t & 15) * 4];
            #pragma unroll
            for (int it = 0; it < 16; ++it)
                wb_r[it] = *(const float4*)&W[(size_t)(it * 16 + (t >> 4)) * 256 + k0 + (t & 15) * 4];
        }
        #pragma unroll
        for (int kk = 0; kk < 2; ++kk) {
            bf16x8 af[4], bfr[4];
            #pragma unroll
            for (int ri = 0; ri < 4; ++ri)
                af[ri] = *(const bf16x8*)&hA[(ri * 16 + ln) * 72 + kk * 32 + quad * 8];
            #pragma unroll
            for (int oi = 0; oi < 4; ++oi)
                bfr[oi] = *(const bf16x8*)&hB[(w * 64 + oi * 16 + ln) * 72 + kk * 32 + quad * 8];
            #pragma unroll
            for (int ri = 0; ri < 4; ++ri)
                #pragma unroll
                for (int oi = 0; oi < 4; ++oi)
                    acc[ri][oi] = __builtin_amdgcn_mfma_f32_16x16x32_bf16(
                        af[ri], bfr[oi], acc[ri][oi], 0, 0, 0);
        }
        __syncthreads();
    }

    // stage acc -> hB as [o][n_local]
    #pragma unroll
    for (int ri = 0; ri < 4; ++ri) {
        const int n = ri * 16 + quad * 4;
        #pragma unroll
        for (int oi = 0; oi < 4; ++oi) {
            const int o = w * 64 + oi * 16 + ln;
            bf16x4 pv = {(__bf16)acc[ri][oi][0], (__bf16)acc[ri][oi][1],
                         (__bf16)acc[ri][oi][2], (__bf16)acc[ri][oi][3]};
            *(bf16x4*)&hB[o * 72 + n] = pv;
        }
    }
    __syncthreads();

    // coalesced whT writes: 8 rows x 128B per instr
    #pragma unroll
    for (int it = 0; it < 8; ++it) {
        const int o   = w * 64 + it * 8 + (l >> 3);
        const int seg = l & 7;
        const bf16x8 v = *(const bf16x8*)&hB[o * 72 + seg * 8];
        *(bf16x8*)&whT[((size_t)b * 256 + o) * 1024 + n0 + seg * 8] = v;
    }

    // fused si/sj
    {
        float s1 = 0.f, s2 = 0.f;
        #pragma unroll 8
        for (int oi = 0; oi < 64; ++oi) {
            const int o = w * 64 + oi;
            const float v = (float)hB[o * 72 + l];
            s1 += v * a_g[o];
            s2 += v * a_g[256 + o];
        }
        red[w * 64 + l]       = s1;
        red[256 + w * 64 + l] = s2;
    }
    __syncthreads();
    if (t < 64) {
        si[b * 1024 + n0 + t] = red[t] + red[64 + t] + red[128 + t] + red[192 + t];
    } else if (t < 128) {
        const int n = t - 64;
        sj[b * 1024 + n0 + n] = red[256 + n] + red[320 + n] + red[384 + n] + red[448 + n];
    }
}

// ---------------- k3: fused attention (R2 structure, XCD-aware remap) --------
// grid 512 (1D), 256 thr. XCD x (= blockIdx%8, round-robin heuristic) serves
// batches [4x, 4x+4): b = (bx&7)*4 + (bx>>3)/16, i-tile = (bx>>3)%16.
__global__ __launch_bounds__(256) void k3_attn(const u64* __restrict__ mask,
                                               const __bf16* __restrict__ whT,
                                               const float* __restrict__ si_g,
                                               const float* __restrict__ sj_g,
                                               float* __restrict__ out) {
    __shared__ __bf16 lds_w[256 * 72];
    __shared__ __bf16 lds_s[64 * 72];
    __shared__ float  lds_denom[64];
    const int t    = threadIdx.x;
    const int bx   = blockIdx.x;
    const int xcd  = bx & 7;
    const int seq  = bx >> 3;            // 0..63
    const int b    = xcd * 4 + (seq >> 4);
    const int i0   = (seq & 15) * 64;
    const int w    = t >> 6;
    const int l    = t & 63;
    const int ln   = l & 15;
    const int quad = l >> 4;
    const int g    = t >> 4;   // 0..15
    const int j4   = t & 15;   // 0..15

    float si_r[4];
    #pragma unroll
    for (int m = 0; m < 4; ++m) si_r[m] = si_g[b * 1024 + i0 + m * 16 + g];

    float dsum[4] = {0.f, 0.f, 0.f, 0.f};
    f32x4 acc[4][4] = {};
    const __bf16* whTb  = whT + (size_t)b * 256 * 1024;
    const u64*    maskb = mask + ((size_t)b * 1024) * 16;

    // pipeline registers
    bf16x8 vreg[8];
    u64    msk[4];
    float4 sjv;

    // preload chunk 0
    #pragma unroll
    for (int it = 0; it < 8; ++it)
        vreg[it] = *(const bf16x8*)&whTb[(size_t)(it * 32 + (t >> 3)) * 1024 + (t & 7) * 8];
    #pragma unroll
    for (int m = 0; m < 4; ++m) msk[m] = maskb[(size_t)(i0 + m * 16 + g) * 16];
    sjv = *(const float4*)&sj_g[b * 1024 + j4 * 4];

    for (int jc = 0; jc < 16; ++jc) {
        const int j0 = jc * 64;
        // commit staged whT chunk to LDS
        #pragma unroll
        for (int it = 0; it < 8; ++it)
            *(bf16x8*)&lds_w[(it * 32 + (t >> 3)) * 72 + (t & 7) * 8] = vreg[it];
        // S tile: w = adj ? exp(leakyrelu(si+sj)) : 0  (bf16)
        #pragma unroll
        for (int m = 0; m < 4; ++m) {
            const int il   = m * 16 + g;
            const unsigned bits = (unsigned)(msk[m] >> (4 * j4)) & 0xFu;
            float e0 = si_r[m] + sjv.x; e0 = e0 > 0.f ? e0 : ALPHA * e0;
            float e1 = si_r[m] + sjv.y; e1 = e1 > 0.f ? e1 : ALPHA * e1;
            float e2 = si_r[m] + sjv.z; e2 = e2 > 0.f ? e2 : ALPHA * e2;
            float e3 = si_r[m] + sjv.w; e3 = e3 > 0.f ? e3 : ALPHA * e3;
            const float w0 = (bits & 1u) ? __expf(e0) : 0.f;
            const float w1 = (bits & 2u) ? __expf(e1) : 0.f;
            const float w2 = (bits & 4u) ? __expf(e2) : 0.f;
            const float w3 = (bits & 8u) ? __expf(e3) : 0.f;
            bf16x4 pv = {(__bf16)w0, (__bf16)w1, (__bf16)w2, (__bf16)w3};
            dsum[m] += (float)pv[0] + (float)pv[1] + (float)pv[2] + (float)pv[3];
            *(bf16x4*)&lds_s[il * 72 + j4 * 4] = pv;
        }
        __syncthreads();
        // prefetch chunk jc+1 while MFMA runs
        if (jc < 15) {
            const int j1 = j0 + 64;
            #pragma unroll
            for (int it = 0; it < 8; ++it)
                vreg[it] = *(const bf16x8*)&whTb[(size_t)(it * 32 + (t >> 3)) * 1024 + j1 + (t & 7) * 8];
            #pragma unroll
            for (int m = 0; m < 4; ++m)
                msk[m] = maskb[(size_t)(i0 + m * 16 + g) * 16 + jc + 1];
            sjv = *(const float4*)&sj_g[b * 1024 + j1 + j4 * 4];
        }
        // P(64x64) @ Wh(64x256)
        #pragma unroll
        for (int kk = 0; kk < 2; ++kk) {
            bf16x8 af[4], bfr[4];
            #pragma unroll
            for (int ri = 0; ri < 4; ++ri)
                af[ri] = *(const bf16x8*)&lds_s[(ri * 16 + ln) * 72 + kk * 32 + quad * 8];
            #pragma unroll
            for (int oi = 0; oi < 4; ++oi)
                bfr[oi] = *(const bf16x8*)&lds_w[(w * 64 + oi * 16 + ln) * 72 + kk * 32 + quad * 8];
            #pragma unroll
            for (int ri = 0; ri < 4; ++ri)
                #pragma unroll
                for (int oi = 0; oi < 4; ++oi)
                    acc[ri][oi] = __builtin_amdgcn_mfma_f32_16x16x32_bf16(
                        af[ri], bfr[oi], acc[ri][oi], 0, 0, 0);
        }
        __syncthreads();
    }

    // reduce denominators across the 16 j4 lanes per row
    #pragma unroll
    for (int m = 0; m < 4; ++m) {
        float v = dsum[m];
        v += __shfl_xor(v, 1);
        v += __shfl_xor(v, 2);
        v += __shfl_xor(v, 4);
        v += __shfl_xor(v, 8);
        if (j4 == 0) lds_denom[m * 16 + g] = v;
    }
    __syncthreads();
    // epilogue: normalize, ELU, store
    #pragma unroll
    for (int ri = 0; ri < 4; ++ri) {
        #pragma unroll
        for (int q = 0; q < 4; ++q) {
            const int il = ri * 16 + quad * 4 + q;
            const float dinv = 1.0f / fmaxf(lds_denom[il], 1e-30f);
            #pragma unroll
            for (int oi = 0; oi < 4; ++oi) {
                const int o = w * 64 + oi * 16 + ln;
                const float v = acc[ri][oi][q] * dinv;
                const float r = v > 0.f ? v : __expf(v) - 1.f;
                out[((size_t)(b * 1024 + i0 + il)) * 256 + o] = r;
            }
        }
    }
}

extern "C" void kernel_launch(void* const* d_in, const int* in_sizes, int n_in,
                              void* d_out, int out_size, void* d_ws, size_t ws_size,
                              hipStream_t stream) {
    const float* h   = (const float*)d_in[0];
    const int*   adj = (const int*)d_in[1];
    const float* W   = (const float*)d_in[2];
    const float* a   = (const float*)d_in[3];
    float* out = (float*)d_out;

    __bf16* whT  = (__bf16*)d_ws;                                   // 16 MiB
    float*  si   = (float*)((char*)d_ws + (size_t)16777216);        // 128 KiB
    float*  sj   = (float*)((char*)d_ws + (size_t)16777216 + 131072);
    u64*    mask = (u64*)((char*)d_ws + (size_t)16777216 + 262144); // 4 MiB

    k0_mask<<<2048, 256, 0, stream>>>(adj, mask);
    k1_gemm1<<<512, 256, 0, stream>>>(h, W, a, whT, si, sj);
    k3_attn<<<512, 256, 0, stream>>>(mask, whT, si, sj, out);
}